// Round 1
// baseline (79.570 us; speedup 1.0000x reference)
//
#include <hip/hip_runtime.h>

// InnerProductNetwork: x (B, 32, 16) fp32 -> out (B, 496) fp32
// out[b][pidx(i,j)] = dot(x[b,i,:], x[b,j,:]) for i<j.
// Equivalent to upper triangle of G = X @ X^T with X = x[b] (32x16).
// One v_mfma_f32_32x32x16_bf16 per batch computes the full Gram matrix;
// A-frag and B-frag for this shape are the SAME lane data (m=lane&31,
// k=(lane>>5)*8+e), so a single 8-float load feeds both operands.
// Memory-bound: 66 MB total HBM traffic -> ~11 us floor at 6 TB/s.

typedef short bf16x8 __attribute__((ext_vector_type(8)));
typedef float f32x16 __attribute__((ext_vector_type(16)));

#define NFIELD 32
#define EMBED  16
#define NPAIR  496    // 32*31/2
#define BATCH_F 512   // NFIELD*EMBED floats per batch

// fp32 -> bf16 round-to-nearest-even (inputs are finite normals; no NaN path)
static __device__ __forceinline__ unsigned short f2bf(float f) {
  unsigned u = __float_as_uint(f);
  u += 0x7FFFu + ((u >> 16) & 1u);
  return (unsigned short)(u >> 16);
}

__global__ __launch_bounds__(256, 4)
void ipnn_mfma(const float* __restrict__ x, float* __restrict__ out, int nb) {
  // per-wave 2KiB output staging slice (496 floats used, 512 for alignment)
  __shared__ __align__(16) float so[4][BATCH_F];
  const int wave = threadIdx.x >> 6;
  const int lane = threadIdx.x & 63;
  const int b = blockIdx.x * 4 + wave;   // one batch per wave
  const int m = lane & 31;               // field row this lane loads
  const int h = lane >> 5;               // k-half (0: k=0..7, 1: k=8..15)

  if (b < nb) {
    // Load x[b][m][8h .. 8h+8) : 8 floats = 2x float4, directly in MFMA
    // A/B fragment layout. Lanes 0..31 cover rows at k-half 0, 32..63 half 1.
    const float4* gp = (const float4*)(x + (size_t)b * BATCH_F);
    const int fi = m * 4 + h * 2;
    float4 f0 = gp[fi];
    float4 f1 = gp[fi + 1];

    bf16x8 a;
    a[0] = (short)f2bf(f0.x);
    a[1] = (short)f2bf(f0.y);
    a[2] = (short)f2bf(f0.z);
    a[3] = (short)f2bf(f0.w);
    a[4] = (short)f2bf(f1.x);
    a[5] = (short)f2bf(f1.y);
    a[6] = (short)f2bf(f1.z);
    a[7] = (short)f2bf(f1.w);

    f32x16 acc = {};
    // G = X * X^T : A-frag == B-frag (same lane mapping, same k order).
    acc = __builtin_amdgcn_mfma_f32_32x32x16_bf16(a, a, acc, 0, 0, 0);

    // Scatter upper-triangle entries into LDS at their output offsets.
    // C/D layout (m74/m101): col = lane&31, row = (r&3) + 8*(r>>2) + 4*h.
    // (Row/col swap immunity: G is symmetric.)
    float* sw = so[wave];
    const int col = m;
#pragma unroll
    for (int r = 0; r < 16; ++r) {
      const int row = (r & 3) + 8 * (r >> 2) + 4 * h;
      if (row < col) {
        // pidx = sum of row lengths before `row` + (col - row - 1)
        const int pidx = ((row * (63 - row)) >> 1) + (col - row - 1);
        sw[pidx] = acc[r];
      }
    }
  }

  __syncthreads();  // order scatter-writes before readback (block-uniform)

  if (b < nb && lane < 62) {
    // Coalesced readback + store: 496 floats = 62 lanes x 2 float4.
    const float* sw = so[wave];
    float4 v0 = *(const float4*)(sw + 4 * lane);          // dwords [0,248)
    float4 v1 = *(const float4*)(sw + 4 * lane + 248);    // dwords [248,496)
    float4* op = (float4*)(out + (size_t)b * NPAIR);
    op[lane] = v0;
    op[lane + 62] = v1;
  }
}

extern "C" void kernel_launch(void* const* d_in, const int* in_sizes, int n_in,
                              void* d_out, int out_size, void* d_ws, size_t ws_size,
                              hipStream_t stream) {
  const float* x = (const float*)d_in[0];
  float* out = (float*)d_out;
  const int nb = in_sizes[0] / BATCH_F;   // 16384
  const int grid = (nb + 3) / 4;          // 4 batches (waves) per block
  ipnn_mfma<<<grid, 256, 0, stream>>>(x, out, nb);
}